// Round 5
// baseline (945.203 us; speedup 1.0000x reference)
//
#include <hip/hip_runtime.h>
#include <hip/hip_bf16.h>

#define NN 8192
#define DD 512

typedef unsigned short u16;
typedef __bf16 bf16_t;
typedef bf16_t bf16x8 __attribute__((ext_vector_type(8)));
typedef float f32x4 __attribute__((ext_vector_type(4)));

__device__ __forceinline__ float bf2f(u16 h) {
    union { unsigned u; float f; } v; v.u = ((unsigned)h) << 16; return v.f;
}
__device__ __forceinline__ u16 f2bf(float f) {
    union { float f; unsigned u; } v; v.f = f;
    unsigned r = v.u + 0x7fffu + ((v.u >> 16) & 1u);
    return (u16)(r >> 16);
}

// fp32 -> bf16, 8 elems/thread (all tensor sizes are multiples of 2048).
__global__ __launch_bounds__(256) void cvt_kernel(const float* __restrict__ s,
        u16* __restrict__ d, int n) {
    int i = (blockIdx.x * 256 + threadIdx.x) * 8;
    if (i >= n) return;
    float4 a = *(const float4*)(s + i);
    float4 b = *(const float4*)(s + i + 4);
    ushort4 o0 = make_ushort4(f2bf(a.x), f2bf(a.y), f2bf(a.z), f2bf(a.w));
    ushort4 o1 = make_ushort4(f2bf(b.x), f2bf(b.y), f2bf(b.z), f2bf(b.w));
    *(ushort4*)(d + i) = o0;
    *(ushort4*)(d + i + 4) = o1;
}

// C[M][Nc] = act(A[M][K] @ B[Nc][K]^T + bias). bf16 in, fp32 accum, bf16 or fp32 out.
// m97-class async staging: global_load_lds width=16, 128x128 tile, BK=32,
// 256 thr = 4 waves (2x2), wave tile 64x64 = 4x4 MFMA 16x16x32.
template<bool RELU, bool BIAS, bool F32OUT>
__global__ __launch_bounds__(256) void gemm_bt(const u16* __restrict__ A,
        const u16* __restrict__ B, const float* __restrict__ bias,
        void* __restrict__ Cv, int M, int Nc, int K) {
    __shared__ alignas(16) u16 As[128 * 32];
    __shared__ alignas(16) u16 Bs[128 * 32];
    const int t = threadIdx.x;
    const int lane = t & 63;
    const int wave = t >> 6;
    const int wm = (wave >> 1) * 64;
    const int wn = (wave & 1) * 64;
    const int rowA = blockIdx.y * 128;
    const int rowB = blockIdx.x * 128;

    f32x4 acc[4][4] = {};

    const int mrow = lane & 15;
    const int kk = (lane >> 4) * 8;

    for (int k0 = 0; k0 < K; k0 += 32) {
        __syncthreads();  // prev iteration's LDS readers done
        #pragma unroll
        for (int r = 0; r < 2; ++r) {
            int chunk = r * 256 + t;  // lds dst = wave-uniform base + lane*16B
            const u16* srcA = A + (size_t)(rowA + (chunk >> 2)) * K + k0 + (chunk & 3) * 8;
            __builtin_amdgcn_global_load_lds(
                (const __attribute__((address_space(1))) void*)srcA,
                (__attribute__((address_space(3))) void*)(As + chunk * 8), 16, 0, 0);
            const u16* srcB = B + (size_t)(rowB + (chunk >> 2)) * K + k0 + (chunk & 3) * 8;
            __builtin_amdgcn_global_load_lds(
                (const __attribute__((address_space(1))) void*)srcB,
                (__attribute__((address_space(3))) void*)(Bs + chunk * 8), 16, 0, 0);
        }
        __syncthreads();  // drains vmcnt -> LDS valid
        bf16x8 af[4], bfv[4];
        #pragma unroll
        for (int i = 0; i < 4; ++i)
            af[i] = *(const bf16x8*)(As + (wm + i * 16 + mrow) * 32 + kk);
        #pragma unroll
        for (int j = 0; j < 4; ++j)
            bfv[j] = *(const bf16x8*)(Bs + (wn + j * 16 + mrow) * 32 + kk);
        #pragma unroll
        for (int i = 0; i < 4; ++i)
            #pragma unroll
            for (int j = 0; j < 4; ++j)
                acc[i][j] = __builtin_amdgcn_mfma_f32_16x16x32_bf16(af[i], bfv[j], acc[i][j], 0, 0, 0);
    }

    // C/D layout (m89/m91): col = lane&15, row = (lane>>4)*4 + reg
    const int crow0 = rowA + wm + (lane >> 4) * 4;
    const int ccol0 = rowB + wn + (lane & 15);
    #pragma unroll
    for (int j = 0; j < 4; ++j) {
        int col = ccol0 + j * 16;
        float bv = BIAS ? bias[col] : 0.0f;
        #pragma unroll
        for (int i = 0; i < 4; ++i) {
            #pragma unroll
            for (int r = 0; r < 4; ++r) {
                float v = acc[i][j][r] + bv;
                if (RELU) v = fmaxf(v, 0.0f);
                size_t off = (size_t)(crow0 + i * 16 + r) * Nc + col;
                if (F32OUT) ((float*)Cv)[off] = v;
                else        ((u16*)Cv)[off] = f2bf(v);
            }
        }
    }
}

// LayerNorm over D=512; y bf16, g/b fp32; writes seq[n][modality][512] bf16.
__global__ __launch_bounds__(256) void ln_kernel(const u16* __restrict__ y,
        const float* __restrict__ g, const float* __restrict__ b,
        u16* __restrict__ seq, int modality) {
    __shared__ float sred[4];
    int n = blockIdx.x, t = threadIdx.x;
    const u16* yr = y + (size_t)n * DD;
    float x0 = bf2f(yr[t]), x1 = bf2f(yr[t + 256]);
    float s = x0 + x1;
    for (int off = 32; off; off >>= 1) s += __shfl_xor(s, off);
    if ((t & 63) == 0) sred[t >> 6] = s;
    __syncthreads();
    float mean = (sred[0] + sred[1] + sred[2] + sred[3]) * (1.0f / DD);
    __syncthreads();
    float d0 = x0 - mean, d1 = x1 - mean;
    float vs = d0 * d0 + d1 * d1;
    for (int off = 32; off; off >>= 1) vs += __shfl_xor(vs, off);
    if ((t & 63) == 0) sred[t >> 6] = vs;
    __syncthreads();
    float var = (sred[0] + sred[1] + sred[2] + sred[3]) * (1.0f / DD);
    float inv = rsqrtf(var + 1e-5f);
    u16* out = seq + (size_t)n * (2 * DD) + modality * DD;
    out[t]       = f2bf(d0 * inv * g[t]       + b[t]);
    out[t + 256] = f2bf(d1 * inv * g[t + 256] + b[t + 256]);
}

// MHA over 2 tokens, 8 heads of 64. One wave per (node, head). ctxm = mean_t(ctx_t).
__global__ __launch_bounds__(256) void attn_kernel(const u16* __restrict__ qkv,
        u16* __restrict__ ctxm) {
    int gid = blockIdx.x * 4 + (threadIdx.x >> 6);
    int lane = threadIdx.x & 63;
    int n = gid >> 3, h = gid & 7;
    const u16* r0 = qkv + (size_t)(n * 2) * 1536;
    const u16* r1 = r0 + 1536;
    float q0 = bf2f(r0[h * 64 + lane]);
    float k0 = bf2f(r0[512 + h * 64 + lane]);
    float v0 = bf2f(r0[1024 + h * 64 + lane]);
    float q1 = bf2f(r1[h * 64 + lane]);
    float k1 = bf2f(r1[512 + h * 64 + lane]);
    float v1 = bf2f(r1[1024 + h * 64 + lane]);
    float p00 = q0 * k0, p01 = q0 * k1, p10 = q1 * k0, p11 = q1 * k1;
    for (int off = 32; off; off >>= 1) {
        p00 += __shfl_xor(p00, off);
        p01 += __shfl_xor(p01, off);
        p10 += __shfl_xor(p10, off);
        p11 += __shfl_xor(p11, off);
    }
    const float sc = 0.125f;  // 1/sqrt(64)
    float s00 = p00 * sc, s01 = p01 * sc, s10 = p10 * sc, s11 = p11 * sc;
    float m0 = fmaxf(s00, s01), e00 = __expf(s00 - m0), e01 = __expf(s01 - m0);
    float a00 = e00 / (e00 + e01), a01 = e01 / (e00 + e01);
    float m1 = fmaxf(s10, s11), e10 = __expf(s10 - m1), e11 = __expf(s11 - m1);
    float a10 = e10 / (e10 + e11), a11 = e11 / (e10 + e11);
    float c0 = a00 * v0 + a01 * v1;
    float c1 = a10 * v0 + a11 * v1;
    ctxm[(size_t)n * 512 + h * 64 + lane] = f2bf(0.5f * (c0 + c1));
}

// Top-16 + softmax stats, one WAVE per row (4 rows per block), no barriers.
// Per lane: online softmax over its 128 values + min-tracked unsorted top-16
// (ties -> earlier index). Then shfl-reduce (m,l) and 16 wave-argmax rounds.
__global__ __launch_bounds__(256) void topk_f32(const float* __restrict__ S,
        float* __restrict__ topv, int* __restrict__ topi) {
    int row = blockIdx.x * 4 + (threadIdx.x >> 6);
    int lane = threadIdx.x & 63;
    const float* Sr = S + (size_t)row * NN;

    float m = -3e38f, l = 0.0f;
    float lv[16]; int li[16];
    #pragma unroll
    for (int q = 0; q < 16; ++q) { lv[q] = -3e38f; li[q] = 0x7FFFFFFF; }
    float lmin = -3e38f; int lslot = 0, lminIdx = 0x7FFFFFFF;

    for (int p = 0; p < 32; ++p) {
        float4 v4 = *(const float4*)(Sr + p * 256 + lane * 4);
        int jb = p * 256 + lane * 4;
        float vm = fmaxf(fmaxf(v4.x, v4.y), fmaxf(v4.z, v4.w));
        #pragma unroll
        for (int u = 0; u < 4; ++u) {
            float v = (&v4.x)[u];
            // online softmax (always)
            if (v > m) { l = l * __expf(m - v) + 1.0f; m = v; }
            else l += __expf(v - m);
        }
        if (vm > lmin) {
            #pragma unroll
            for (int u = 0; u < 4; ++u) {
                float v = (&v4.x)[u];
                if (v > lmin) {
                    // replace current min slot, then rescan for new min
                    #pragma unroll
                    for (int q = 0; q < 16; ++q)
                        if (q == lslot) { lv[q] = v; li[q] = jb + u; }
                    lmin = lv[0]; lslot = 0; lminIdx = li[0];
                    #pragma unroll
                    for (int q = 1; q < 16; ++q) {
                        bool worse = (lv[q] < lmin) ||
                                     (lv[q] == lmin && li[q] > lminIdx);
                        if (worse) { lmin = lv[q]; lslot = q; lminIdx = li[q]; }
                    }
                }
            }
        }
    }

    // wave-reduce (m, l)
    #pragma unroll
    for (int off = 32; off; off >>= 1) {
        float om = __shfl_xor(m, off);
        float ol = __shfl_xor(l, off);
        float nm = fmaxf(m, om);
        l = l * __expf(m - nm) + ol * __expf(om - nm);
        m = nm;
    }

    // 16 extraction rounds
    for (int r = 0; r < 16; ++r) {
        float bm = lv[0]; int bi = li[0];
        #pragma unroll
        for (int q = 1; q < 16; ++q)
            if (lv[q] > bm || (lv[q] == bm && li[q] < bi)) { bm = lv[q]; bi = li[q]; }
        float cv = bm; int ci = bi;
        #pragma unroll
        for (int off = 32; off; off >>= 1) {
            float ov = __shfl_xor(cv, off);
            int oi = __shfl_xor(ci, off);
            if (ov > cv || (ov == cv && oi < ci)) { cv = ov; ci = oi; }
        }
        if (lane == 0) {
            topv[(size_t)row * 16 + r] = __expf(cv - m) / l;
            topi[(size_t)row * 16 + r] = ci;
        }
        #pragma unroll
        for (int q = 0; q < 16; ++q)
            if (li[q] == ci) lv[q] = -3e38f;  // owner removes (indices unique)
    }
}

// H fp32: zero everything, diag = 1.0f. 8 floats/thread.
__global__ __launch_bounds__(256) void zero_diag_f32(float* __restrict__ H) {
    size_t e = ((size_t)blockIdx.x * 256 + threadIdx.x) * 8;
    int r = (int)(e >> 13);
    int c0 = (int)(e & (NN - 1));
    float4 z0 = make_float4(0.f, 0.f, 0.f, 0.f);
    float4 z1 = z0;
    if (r >= c0 && r < c0 + 8) {
        int o = r - c0;
        float* p = (o < 4) ? ((float*)&z0) + o : ((float*)&z1) + (o - 4);
        *p = 1.0f;
    }
    *(float4*)(H + e) = z0;
    *(float4*)(H + e + 4) = z1;
}

__global__ __launch_bounds__(256) void scatter_kernel(const float* __restrict__ topv,
        const int* __restrict__ topi, float* __restrict__ H) {
    int tk = blockIdx.x * 256 + threadIdx.x;  // 8192*16
    int i = tk >> 4;
    int idx = topi[tk];
    H[(size_t)idx * NN + i] = topv[tk];
}

// ew = max(sigmoid(hidden @ w2 + b2), 1e-8), fp32 out. One wave per node.
__global__ __launch_bounds__(256) void ew_kernel(const u16* __restrict__ hidden,
        const float* __restrict__ w2, const float* __restrict__ b2, float* __restrict__ out) {
    int n = blockIdx.x * 4 + (threadIdx.x >> 6);
    int lane = threadIdx.x & 63;
    const u16* hr = hidden + (size_t)n * 256;
    float s = 0.0f;
    #pragma unroll
    for (int p = 0; p < 4; ++p) s += bf2f(hr[lane + p * 64]) * w2[lane + p * 64];
    for (int off = 32; off; off >>= 1) s += __shfl_xor(s, off);
    if (lane == 0) {
        float z = s + b2[0];
        float sig = 1.0f / (1.0f + __expf(-z));
        out[n] = fmaxf(sig, 1e-8f);
    }
}

extern "C" void kernel_launch(void* const* d_in, const int* in_sizes, int n_in,
                              void* d_out, int out_size, void* d_ws, size_t ws_size,
                              hipStream_t stream) {
    const float* x0    = (const float*)d_in[0];
    const float* x1    = (const float*)d_in[1];
    const float* w_p0  = (const float*)d_in[2];
    const float* b_p0  = (const float*)d_in[3];
    const float* g0    = (const float*)d_in[4];
    const float* beta0 = (const float*)d_in[5];
    const float* w_p1  = (const float*)d_in[6];
    const float* b_p1  = (const float*)d_in[7];
    const float* g1    = (const float*)d_in[8];
    const float* beta1 = (const float*)d_in[9];
    const float* in_w  = (const float*)d_in[10];
    const float* in_b  = (const float*)d_in[11];
    const float* out_w = (const float*)d_in[12];
    const float* out_b = (const float*)d_in[13];
    const float* ew_w1 = (const float*)d_in[14];
    const float* ew_b1 = (const float*)d_in[15];
    const float* ew_w2 = (const float*)d_in[16];
    const float* ew_b2 = (const float*)d_in[17];

    float* Hf = (float*)d_out;                  // [8192][8192] fp32 (256 MB)
    float* ew_out = Hf + (size_t)NN * NN;       // [8192] fp32

    // bf16 staging inside the fp32 H region (dead before S fp32 overwrites all of H).
    u16* Hu = (u16*)d_out;
    u16* x0b    = Hu;                           //   0.. 8 MB   8192x512 bf16
    u16* x1b    = Hu + 4194304;                 //   8..16 MB
    u16* y0     = Hu + 8388608;                 //  16..24 MB
    u16* y1     = Hu + 12582912;                //  24..32 MB
    u16* seq    = Hu + 16777216;                //  32..48 MB   [16384][512]
    u16* qkv    = Hu + 25165824;                //  48..96 MB   [16384][1536]
    u16* ctxm   = Hu + 50331648;                //  96..104 MB
    u16* hidden = Hu + 54525952;                // 104..108 MB  [8192][256]
    u16* wp0b   = Hu + 60817408;                // 116 MB.. weights (3.25 MB)
    u16* wp1b   = wp0b + 262144;
    u16* inwb   = wp1b + 262144;                // [1536][512]
    u16* outwb  = inwb + 786432;
    u16* eww1b  = outwb + 262144;               // [256][512]
    // ws: survives the S GEMM (9 MB)
    char* ws = (char*)d_ws;
    u16* fusedB = (u16*)ws;                     // [8192][512] bf16, 8 MB
    float* topv = (float*)(ws + (8u << 20));    // [8192][16]
    int*   topi = (int*)(ws + (8u << 20) + 524288);

    dim3 blk(256);
    // 0: fp32 -> bf16 for all MFMA operands
    cvt_kernel<<<dim3(2048), blk, 0, stream>>>(x0, x0b, 4194304);
    cvt_kernel<<<dim3(2048), blk, 0, stream>>>(x1, x1b, 4194304);
    cvt_kernel<<<dim3(128),  blk, 0, stream>>>(w_p0, wp0b, 262144);
    cvt_kernel<<<dim3(128),  blk, 0, stream>>>(w_p1, wp1b, 262144);
    cvt_kernel<<<dim3(384),  blk, 0, stream>>>(in_w, inwb, 786432);
    cvt_kernel<<<dim3(128),  blk, 0, stream>>>(out_w, outwb, 262144);
    cvt_kernel<<<dim3(64),   blk, 0, stream>>>(ew_w1, eww1b, 131072);
    // 1-2: modality projections (relu fused)
    gemm_bt<true, true, false><<<dim3(4, 64), blk, 0, stream>>>(x0b, wp0b, b_p0, y0, NN, DD, DD);
    gemm_bt<true, true, false><<<dim3(4, 64), blk, 0, stream>>>(x1b, wp1b, b_p1, y1, NN, DD, DD);
    // 3-4: LayerNorm -> seq
    ln_kernel<<<dim3(NN), blk, 0, stream>>>(y0, g0, beta0, seq, 0);
    ln_kernel<<<dim3(NN), blk, 0, stream>>>(y1, g1, beta1, seq, 1);
    // 5: qkv = seq @ in_w^T + in_b  (M=16384, N=1536)
    gemm_bt<false, true, false><<<dim3(12, 128), blk, 0, stream>>>(seq, inwb, in_b, qkv, 2 * NN, 1536, DD);
    // 6: attention -> ctxm = mean_t ctx
    attn_kernel<<<dim3(NN * 8 / 4), blk, 0, stream>>>(qkv, ctxm);
    // 7: fused = ctxm @ out_w^T + out_b (out-proj commutes with token mean)
    gemm_bt<false, true, false><<<dim3(4, 64), blk, 0, stream>>>(ctxm, outwb, out_b, fusedB, NN, DD, DD);
    // 8: hidden = relu(fused @ ew_w1^T + ew_b1)
    gemm_bt<true, true, false><<<dim3(2, 64), blk, 0, stream>>>(fusedB, eww1b, ew_b1, hidden, NN, 256, DD);
    // 9: ew -> fp32 tail of d_out
    ew_kernel<<<dim3(NN / 4), blk, 0, stream>>>(hidden, ew_w2, ew_b2, ew_out);
    // 10: S = fused @ fused^T, fp32, into the FULL H region (staging all dead)
    gemm_bt<false, false, true><<<dim3(64, 64), blk, 0, stream>>>(fusedB, fusedB, nullptr, Hf, NN, NN, DD);
    // 11: per-row softmax stats + top-16 (wave per row)
    topk_f32<<<dim3(NN / 4), blk, 0, stream>>>(Hf, topv, topi);
    // 12: H := 0 (fp32), diag := 1.0f
    zero_diag_f32<<<dim3(NN * NN / 8 / 256), blk, 0, stream>>>(Hf);
    // 13: H[idx[i,j], i] = vals[i,j]
    scatter_kernel<<<dim3(NN * 16 / 256), blk, 0, stream>>>(topv, topi, Hf);
}

// Round 6
// 842.339 us; speedup vs baseline: 1.1221x; 1.1221x over previous
//
#include <hip/hip_runtime.h>
#include <hip/hip_bf16.h>

#define NN 8192
#define DD 512

typedef unsigned short u16;
typedef __bf16 bf16_t;
typedef bf16_t bf16x8 __attribute__((ext_vector_type(8)));
typedef float f32x4 __attribute__((ext_vector_type(4)));

__device__ __forceinline__ float bf2f(u16 h) {
    union { unsigned u; float f; } v; v.u = ((unsigned)h) << 16; return v.f;
}
__device__ __forceinline__ u16 f2bf(float f) {
    union { float f; unsigned u; } v; v.f = f;
    unsigned r = v.u + 0x7fffu + ((v.u >> 16) & 1u);
    return (u16)(r >> 16);
}

// fp32 -> bf16, 8 elems/thread (all tensor sizes are multiples of 2048).
__global__ __launch_bounds__(256) void cvt_kernel(const float* __restrict__ s,
        u16* __restrict__ d, int n) {
    int i = (blockIdx.x * 256 + threadIdx.x) * 8;
    if (i >= n) return;
    float4 a = *(const float4*)(s + i);
    float4 b = *(const float4*)(s + i + 4);
    ushort4 o0 = make_ushort4(f2bf(a.x), f2bf(a.y), f2bf(a.z), f2bf(a.w));
    ushort4 o1 = make_ushort4(f2bf(b.x), f2bf(b.y), f2bf(b.z), f2bf(b.w));
    *(ushort4*)(d + i) = o0;
    *(ushort4*)(d + i + 4) = o1;
}

// C[M][Nc] = act(A[M][K] @ B[Nc][K]^T + bias). bf16 in, fp32 accum, bf16/fp32 out.
// m97-class async staging: global_load_lds width=16, 128x128 tile, BK=32,
// 256 thr = 4 waves (2x2), wave tile 64x64 = 4x4 MFMA 16x16x32.
template<bool RELU, bool BIAS, bool F32OUT>
__global__ __launch_bounds__(256) void gemm_bt(const u16* __restrict__ A,
        const u16* __restrict__ B, const float* __restrict__ bias,
        void* __restrict__ Cv, int M, int Nc, int K) {
    __shared__ alignas(16) u16 As[128 * 32];
    __shared__ alignas(16) u16 Bs[128 * 32];
    const int t = threadIdx.x;
    const int lane = t & 63;
    const int wave = t >> 6;
    const int wm = (wave >> 1) * 64;
    const int wn = (wave & 1) * 64;
    const int rowA = blockIdx.y * 128;
    const int rowB = blockIdx.x * 128;

    f32x4 acc[4][4] = {};

    const int mrow = lane & 15;
    const int kk = (lane >> 4) * 8;

    for (int k0 = 0; k0 < K; k0 += 32) {
        __syncthreads();
        #pragma unroll
        for (int r = 0; r < 2; ++r) {
            int chunk = r * 256 + t;
            const u16* srcA = A + (size_t)(rowA + (chunk >> 2)) * K + k0 + (chunk & 3) * 8;
            __builtin_amdgcn_global_load_lds(
                (const __attribute__((address_space(1))) void*)srcA,
                (__attribute__((address_space(3))) void*)(As + chunk * 8), 16, 0, 0);
            const u16* srcB = B + (size_t)(rowB + (chunk >> 2)) * K + k0 + (chunk & 3) * 8;
            __builtin_amdgcn_global_load_lds(
                (const __attribute__((address_space(1))) void*)srcB,
                (__attribute__((address_space(3))) void*)(Bs + chunk * 8), 16, 0, 0);
        }
        __syncthreads();
        bf16x8 af[4], bfv[4];
        #pragma unroll
        for (int i = 0; i < 4; ++i)
            af[i] = *(const bf16x8*)(As + (wm + i * 16 + mrow) * 32 + kk);
        #pragma unroll
        for (int j = 0; j < 4; ++j)
            bfv[j] = *(const bf16x8*)(Bs + (wn + j * 16 + mrow) * 32 + kk);
        #pragma unroll
        for (int i = 0; i < 4; ++i)
            #pragma unroll
            for (int j = 0; j < 4; ++j)
                acc[i][j] = __builtin_amdgcn_mfma_f32_16x16x32_bf16(af[i], bfv[j], acc[i][j], 0, 0, 0);
    }

    // C/D layout (m89/m91): col = lane&15, row = (lane>>4)*4 + reg
    const int crow0 = rowA + wm + (lane >> 4) * 4;
    const int ccol0 = rowB + wn + (lane & 15);
    #pragma unroll
    for (int j = 0; j < 4; ++j) {
        int col = ccol0 + j * 16;
        float bv = BIAS ? bias[col] : 0.0f;
        #pragma unroll
        for (int i = 0; i < 4; ++i) {
            #pragma unroll
            for (int r = 0; r < 4; ++r) {
                float v = acc[i][j][r] + bv;
                if (RELU) v = fmaxf(v, 0.0f);
                size_t off = (size_t)(crow0 + i * 16 + r) * Nc + col;
                if (F32OUT) ((float*)Cv)[off] = v;
                else        ((u16*)Cv)[off] = f2bf(v);
            }
        }
    }
}

// LayerNorm over D=512; y bf16, g/b fp32; writes seq[n][modality][512] bf16.
__global__ __launch_bounds__(256) void ln_kernel(const u16* __restrict__ y,
        const float* __restrict__ g, const float* __restrict__ b,
        u16* __restrict__ seq, int modality) {
    __shared__ float sred[4];
    int n = blockIdx.x, t = threadIdx.x;
    const u16* yr = y + (size_t)n * DD;
    float x0 = bf2f(yr[t]), x1 = bf2f(yr[t + 256]);
    float s = x0 + x1;
    for (int off = 32; off; off >>= 1) s += __shfl_xor(s, off);
    if ((t & 63) == 0) sred[t >> 6] = s;
    __syncthreads();
    float mean = (sred[0] + sred[1] + sred[2] + sred[3]) * (1.0f / DD);
    __syncthreads();
    float d0 = x0 - mean, d1 = x1 - mean;
    float vs = d0 * d0 + d1 * d1;
    for (int off = 32; off; off >>= 1) vs += __shfl_xor(vs, off);
    if ((t & 63) == 0) sred[t >> 6] = vs;
    __syncthreads();
    float var = (sred[0] + sred[1] + sred[2] + sred[3]) * (1.0f / DD);
    float inv = rsqrtf(var + 1e-5f);
    u16* out = seq + (size_t)n * (2 * DD) + modality * DD;
    out[t]       = f2bf(d0 * inv * g[t]       + b[t]);
    out[t + 256] = f2bf(d1 * inv * g[t + 256] + b[t + 256]);
}

// MHA over 2 tokens, 8 heads of 64. One wave per (node, head). ctxm = mean_t(ctx_t).
__global__ __launch_bounds__(256) void attn_kernel(const u16* __restrict__ qkv,
        u16* __restrict__ ctxm) {
    int gid = blockIdx.x * 4 + (threadIdx.x >> 6);
    int lane = threadIdx.x & 63;
    int n = gid >> 3, h = gid & 7;
    const u16* r0 = qkv + (size_t)(n * 2) * 1536;
    const u16* r1 = r0 + 1536;
    float q0 = bf2f(r0[h * 64 + lane]);
    float k0 = bf2f(r0[512 + h * 64 + lane]);
    float v0 = bf2f(r0[1024 + h * 64 + lane]);
    float q1 = bf2f(r1[h * 64 + lane]);
    float k1 = bf2f(r1[512 + h * 64 + lane]);
    float v1 = bf2f(r1[1024 + h * 64 + lane]);
    float p00 = q0 * k0, p01 = q0 * k1, p10 = q1 * k0, p11 = q1 * k1;
    for (int off = 32; off; off >>= 1) {
        p00 += __shfl_xor(p00, off);
        p01 += __shfl_xor(p01, off);
        p10 += __shfl_xor(p10, off);
        p11 += __shfl_xor(p11, off);
    }
    const float sc = 0.125f;  // 1/sqrt(64)
    float s00 = p00 * sc, s01 = p01 * sc, s10 = p10 * sc, s11 = p11 * sc;
    float m0 = fmaxf(s00, s01), e00 = __expf(s00 - m0), e01 = __expf(s01 - m0);
    float a00 = e00 / (e00 + e01), a01 = e01 / (e00 + e01);
    float m1 = fmaxf(s10, s11), e10 = __expf(s10 - m1), e11 = __expf(s11 - m1);
    float a10 = e10 / (e10 + e11), a11 = e11 / (e10 + e11);
    float c0 = a00 * v0 + a01 * v1;
    float c1 = a10 * v0 + a11 * v1;
    ctxm[(size_t)n * 512 + h * 64 + lane] = f2bf(0.5f * (c0 + c1));
}

// Top-16 + softmax stats. Block per row; LDS row cache; lazy two-level extraction.
// No dynamically-indexed per-thread arrays (spill-free), branchless sumexp.
__global__ __launch_bounds__(256) void topk_sel(const float* __restrict__ S,
        float* __restrict__ topv, int* __restrict__ topi) {
    __shared__ float rowS[NN];      // 32 KB
    __shared__ float curv[256];     // per-thread current best value
    __shared__ int   curi[256];     // its column index
    __shared__ float sred[8];
    int row = blockIdx.x, t = threadIdx.x;
    int lane = t & 63, wave = t >> 6;
    const float* Sr = S + (size_t)row * NN;

    // pass 1: load (coalesced float4), keep in regs (static indexing), mirror to LDS
    float4 vals[8];
    float lmax = -3e38f, bestv = -3e38f;
    int besti = 0;
    #pragma unroll
    for (int p = 0; p < 8; ++p) {
        float4 v = *(const float4*)(Sr + p * 1024 + t * 4);
        vals[p] = v;
        *(float4*)(rowS + p * 1024 + t * 4) = v;
        #pragma unroll
        for (int u = 0; u < 4; ++u) {
            float x = (&v.x)[u];
            lmax = fmaxf(lmax, x);
            if (x > bestv) { bestv = x; besti = p * 1024 + t * 4 + u; }  // ascending idx -> tie keeps earlier
        }
    }
    #pragma unroll
    for (int off = 32; off; off >>= 1) lmax = fmaxf(lmax, __shfl_xor(lmax, off));
    if (lane == 0) sred[wave] = lmax;
    __syncthreads();
    float m = fmaxf(fmaxf(sred[0], sred[1]), fmaxf(sred[2], sred[3]));

    // pass 2: branchless sumexp from registers
    float ls = 0.0f;
    #pragma unroll
    for (int p = 0; p < 8; ++p)
        ls += __expf(vals[p].x - m) + __expf(vals[p].y - m)
            + __expf(vals[p].z - m) + __expf(vals[p].w - m);
    #pragma unroll
    for (int off = 32; off; off >>= 1) ls += __shfl_xor(ls, off);
    if (lane == 0) sred[4 + wave] = ls;
    curv[t] = bestv;
    curi[t] = besti;
    __syncthreads();
    float l = sred[4] + sred[5] + sred[6] + sred[7];

    // 16 extraction rounds: argmax over 256 candidates, only the owner rescans.
    for (int r = 0; r < 16; ++r) {
        float bv = -3e38f; int bi = 0x7FFFFFFF, be = 0;
        #pragma unroll
        for (int w = 0; w < 4; ++w) {
            int e = w * 64 + lane;
            float v = curv[e]; int ii = curi[e];
            if (v > bv || (v == bv && ii < bi)) { bv = v; bi = ii; be = e; }
        }
        #pragma unroll
        for (int off = 32; off; off >>= 1) {
            float ov = __shfl_xor(bv, off);
            int oi = __shfl_xor(bi, off);
            int oe = __shfl_xor(be, off);
            if (ov > bv || (ov == bv && oi < bi)) { bv = ov; bi = oi; be = oe; }
        }
        if (t == 0) {
            topv[(size_t)row * 16 + r] = __expf(bv - m) / l;
            topi[(size_t)row * 16 + r] = bi;
        }
        if (t == be) {  // owner: remove extracted elem, recompute its local top-1
            rowS[bi] = -3e38f;
            float nb = -3e38f; int ni = 0;
            #pragma unroll
            for (int p = 0; p < 8; ++p) {
                float4 v = *(const float4*)(rowS + p * 1024 + t * 4);
                #pragma unroll
                for (int u = 0; u < 4; ++u) {
                    float x = (&v.x)[u];
                    if (x > nb) { nb = x; ni = p * 1024 + t * 4 + u; }
                }
            }
            curv[t] = nb;
            curi[t] = ni;
        }
        __syncthreads();
    }
}

// H fp32: zero everything, diag = 1.0f. 8 floats/thread.
__global__ __launch_bounds__(256) void zero_diag_f32(float* __restrict__ H) {
    size_t e = ((size_t)blockIdx.x * 256 + threadIdx.x) * 8;
    int r = (int)(e >> 13);
    int c0 = (int)(e & (NN - 1));
    float4 z0 = make_float4(0.f, 0.f, 0.f, 0.f);
    float4 z1 = z0;
    if (r >= c0 && r < c0 + 8) {
        int o = r - c0;
        float* p = (o < 4) ? ((float*)&z0) + o : ((float*)&z1) + (o - 4);
        *p = 1.0f;
    }
    *(float4*)(H + e) = z0;
    *(float4*)(H + e + 4) = z1;
}

__global__ __launch_bounds__(256) void scatter_kernel(const float* __restrict__ topv,
        const int* __restrict__ topi, float* __restrict__ H) {
    int tk = blockIdx.x * 256 + threadIdx.x;  // 8192*16
    int i = tk >> 4;
    int idx = topi[tk];
    H[(size_t)idx * NN + i] = topv[tk];
}

// ew = max(sigmoid(hidden @ w2 + b2), 1e-8), fp32 out. One wave per node.
__global__ __launch_bounds__(256) void ew_kernel(const u16* __restrict__ hidden,
        const float* __restrict__ w2, const float* __restrict__ b2, float* __restrict__ out) {
    int n = blockIdx.x * 4 + (threadIdx.x >> 6);
    int lane = threadIdx.x & 63;
    const u16* hr = hidden + (size_t)n * 256;
    float s = 0.0f;
    #pragma unroll
    for (int p = 0; p < 4; ++p) s += bf2f(hr[lane + p * 64]) * w2[lane + p * 64];
    for (int off = 32; off; off >>= 1) s += __shfl_xor(s, off);
    if (lane == 0) {
        float z = s + b2[0];
        float sig = 1.0f / (1.0f + __expf(-z));
        out[n] = fmaxf(sig, 1e-8f);
    }
}

extern "C" void kernel_launch(void* const* d_in, const int* in_sizes, int n_in,
                              void* d_out, int out_size, void* d_ws, size_t ws_size,
                              hipStream_t stream) {
    const float* x0    = (const float*)d_in[0];
    const float* x1    = (const float*)d_in[1];
    const float* w_p0  = (const float*)d_in[2];
    const float* b_p0  = (const float*)d_in[3];
    const float* g0    = (const float*)d_in[4];
    const float* beta0 = (const float*)d_in[5];
    const float* w_p1  = (const float*)d_in[6];
    const float* b_p1  = (const float*)d_in[7];
    const float* g1    = (const float*)d_in[8];
    const float* beta1 = (const float*)d_in[9];
    const float* in_w  = (const float*)d_in[10];
    const float* in_b  = (const float*)d_in[11];
    const float* out_w = (const float*)d_in[12];
    const float* out_b = (const float*)d_in[13];
    const float* ew_w1 = (const float*)d_in[14];
    const float* ew_b1 = (const float*)d_in[15];
    const float* ew_w2 = (const float*)d_in[16];
    const float* ew_b2 = (const float*)d_in[17];

    float* Hf = (float*)d_out;                  // [8192][8192] fp32 (256 MB)
    float* ew_out = Hf + (size_t)NN * NN;       // [8192] fp32

    // bf16 staging inside the fp32 H region (dead before S fp32 overwrites all of H).
    u16* Hu = (u16*)d_out;
    u16* x0b    = Hu;                           //   0.. 8 MB
    u16* x1b    = Hu + 4194304;                 //   8..16 MB
    u16* y0     = Hu + 8388608;                 //  16..24 MB
    u16* y1     = Hu + 12582912;                //  24..32 MB
    u16* seq    = Hu + 16777216;                //  32..48 MB   [16384][512]
    u16* qkv    = Hu + 25165824;                //  48..96 MB   [16384][1536]
    u16* ctxm   = Hu + 50331648;                //  96..104 MB
    u16* hidden = Hu + 54525952;                // 104..108 MB  [8192][256]
    u16* wp0b   = Hu + 60817408;                // 116 MB.. weights (3.25 MB)
    u16* wp1b   = wp0b + 262144;
    u16* inwb   = wp1b + 262144;                // [1536][512]
    u16* outwb  = inwb + 786432;
    u16* eww1b  = outwb + 262144;               // [256][512]
    // ws: survives the S GEMM (9 MB)
    char* ws = (char*)d_ws;
    u16* fusedB = (u16*)ws;                     // [8192][512] bf16, 8 MB
    float* topv = (float*)(ws + (8u << 20));    // [8192][16]
    int*   topi = (int*)(ws + (8u << 20) + 524288);

    dim3 blk(256);
    // 0: fp32 -> bf16 for all MFMA operands
    cvt_kernel<<<dim3(2048), blk, 0, stream>>>(x0, x0b, 4194304);
    cvt_kernel<<<dim3(2048), blk, 0, stream>>>(x1, x1b, 4194304);
    cvt_kernel<<<dim3(128),  blk, 0, stream>>>(w_p0, wp0b, 262144);
    cvt_kernel<<<dim3(128),  blk, 0, stream>>>(w_p1, wp1b, 262144);
    cvt_kernel<<<dim3(384),  blk, 0, stream>>>(in_w, inwb, 786432);
    cvt_kernel<<<dim3(128),  blk, 0, stream>>>(out_w, outwb, 262144);
    cvt_kernel<<<dim3(64),   blk, 0, stream>>>(ew_w1, eww1b, 131072);
    // 1-2: modality projections (relu fused)
    gemm_bt<true, true, false><<<dim3(4, 64), blk, 0, stream>>>(x0b, wp0b, b_p0, y0, NN, DD, DD);
    gemm_bt<true, true, false><<<dim3(4, 64), blk, 0, stream>>>(x1b, wp1b, b_p1, y1, NN, DD, DD);
    // 3-4: LayerNorm -> seq
    ln_kernel<<<dim3(NN), blk, 0, stream>>>(y0, g0, beta0, seq, 0);
    ln_kernel<<<dim3(NN), blk, 0, stream>>>(y1, g1, beta1, seq, 1);
    // 5: qkv = seq @ in_w^T + in_b  (M=16384, N=1536)
    gemm_bt<false, true, false><<<dim3(12, 128), blk, 0, stream>>>(seq, inwb, in_b, qkv, 2 * NN, 1536, DD);
    // 6: attention -> ctxm = mean_t ctx
    attn_kernel<<<dim3(NN * 8 / 4), blk, 0, stream>>>(qkv, ctxm);
    // 7: fused = ctxm @ out_w^T + out_b (out-proj commutes with token mean)
    gemm_bt<false, true, false><<<dim3(4, 64), blk, 0, stream>>>(ctxm, outwb, out_b, fusedB, NN, DD, DD);
    // 8: hidden = relu(fused @ ew_w1^T + ew_b1)
    gemm_bt<true, true, false><<<dim3(2, 64), blk, 0, stream>>>(fusedB, eww1b, ew_b1, hidden, NN, 256, DD);
    // 9: ew -> fp32 tail of d_out
    ew_kernel<<<dim3(NN / 4), blk, 0, stream>>>(hidden, ew_w2, ew_b2, ew_out);
    // 10: S = fused @ fused^T, fp32, into the FULL H region (staging all dead)
    gemm_bt<false, false, true><<<dim3(64, 64), blk, 0, stream>>>(fusedB, fusedB, nullptr, Hf, NN, NN, DD);
    // 11: per-row softmax stats + top-16 (block per row, LDS row cache)
    topk_sel<<<dim3(NN), blk, 0, stream>>>(Hf, topv, topi);
    // 12: H := 0 (fp32), diag := 1.0f
    zero_diag_f32<<<dim3(NN * NN / 8 / 256), blk, 0, stream>>>(Hf);
    // 13: H[idx[i,j], i] = vals[i,j]
    scatter_kernel<<<dim3(NN * 16 / 256), blk, 0, stream>>>(topv, topi, Hf);
}

// Round 7
// 816.007 us; speedup vs baseline: 1.1583x; 1.0323x over previous
//
#include <hip/hip_runtime.h>
#include <hip/hip_bf16.h>

#define NN 8192
#define DD 512

typedef unsigned short u16;
typedef __bf16 bf16_t;
typedef bf16_t bf16x8 __attribute__((ext_vector_type(8)));
typedef float f32x4 __attribute__((ext_vector_type(4)));

__device__ __forceinline__ float bf2f(u16 h) {
    union { unsigned u; float f; } v; v.u = ((unsigned)h) << 16; return v.f;
}
__device__ __forceinline__ u16 f2bf(float f) {
    union { float f; unsigned u; } v; v.f = f;
    unsigned r = v.u + 0x7fffu + ((v.u >> 16) & 1u);
    return (u16)(r >> 16);
}

// fp32 -> bf16, 8 elems/thread (all tensor sizes are multiples of 2048).
__global__ __launch_bounds__(256) void cvt_kernel(const float* __restrict__ s,
        u16* __restrict__ d, int n) {
    int i = (blockIdx.x * 256 + threadIdx.x) * 8;
    if (i >= n) return;
    float4 a = *(const float4*)(s + i);
    float4 b = *(const float4*)(s + i + 4);
    ushort4 o0 = make_ushort4(f2bf(a.x), f2bf(a.y), f2bf(a.z), f2bf(a.w));
    ushort4 o1 = make_ushort4(f2bf(b.x), f2bf(b.y), f2bf(b.z), f2bf(b.w));
    *(ushort4*)(d + i) = o0;
    *(ushort4*)(d + i + 4) = o1;
}

// C[M][Nc] = act(A[M][K] @ B[Nc][K]^T + bias). bf16 in, fp32 accum, bf16/fp32 out.
// m97-class async staging: global_load_lds width=16, 128x128 tile, BK=32,
// 256 thr = 4 waves (2x2), wave tile 64x64 = 4x4 MFMA 16x16x32.
template<bool RELU, bool BIAS, bool F32OUT>
__global__ __launch_bounds__(256) void gemm_bt(const u16* __restrict__ A,
        const u16* __restrict__ B, const float* __restrict__ bias,
        void* __restrict__ Cv, int M, int Nc, int K) {
    __shared__ alignas(16) u16 As[128 * 32];
    __shared__ alignas(16) u16 Bs[128 * 32];
    const int t = threadIdx.x;
    const int lane = t & 63;
    const int wave = t >> 6;
    const int wm = (wave >> 1) * 64;
    const int wn = (wave & 1) * 64;
    const int rowA = blockIdx.y * 128;
    const int rowB = blockIdx.x * 128;

    f32x4 acc[4][4] = {};

    const int mrow = lane & 15;
    const int kk = (lane >> 4) * 8;

    for (int k0 = 0; k0 < K; k0 += 32) {
        __syncthreads();
        #pragma unroll
        for (int r = 0; r < 2; ++r) {
            int chunk = r * 256 + t;
            const u16* srcA = A + (size_t)(rowA + (chunk >> 2)) * K + k0 + (chunk & 3) * 8;
            __builtin_amdgcn_global_load_lds(
                (const __attribute__((address_space(1))) void*)srcA,
                (__attribute__((address_space(3))) void*)(As + chunk * 8), 16, 0, 0);
            const u16* srcB = B + (size_t)(rowB + (chunk >> 2)) * K + k0 + (chunk & 3) * 8;
            __builtin_amdgcn_global_load_lds(
                (const __attribute__((address_space(1))) void*)srcB,
                (__attribute__((address_space(3))) void*)(Bs + chunk * 8), 16, 0, 0);
        }
        __syncthreads();
        bf16x8 af[4], bfv[4];
        #pragma unroll
        for (int i = 0; i < 4; ++i)
            af[i] = *(const bf16x8*)(As + (wm + i * 16 + mrow) * 32 + kk);
        #pragma unroll
        for (int j = 0; j < 4; ++j)
            bfv[j] = *(const bf16x8*)(Bs + (wn + j * 16 + mrow) * 32 + kk);
        #pragma unroll
        for (int i = 0; i < 4; ++i)
            #pragma unroll
            for (int j = 0; j < 4; ++j)
                acc[i][j] = __builtin_amdgcn_mfma_f32_16x16x32_bf16(af[i], bfv[j], acc[i][j], 0, 0, 0);
    }

    // C/D layout (m89/m91): col = lane&15, row = (lane>>4)*4 + reg
    const int crow0 = rowA + wm + (lane >> 4) * 4;
    const int ccol0 = rowB + wn + (lane & 15);
    #pragma unroll
    for (int j = 0; j < 4; ++j) {
        int col = ccol0 + j * 16;
        float bv = BIAS ? bias[col] : 0.0f;
        #pragma unroll
        for (int i = 0; i < 4; ++i) {
            #pragma unroll
            for (int r = 0; r < 4; ++r) {
                float v = acc[i][j][r] + bv;
                if (RELU) v = fmaxf(v, 0.0f);
                size_t off = (size_t)(crow0 + i * 16 + r) * Nc + col;
                if (F32OUT) ((float*)Cv)[off] = v;
                else        ((u16*)Cv)[off] = f2bf(v);
            }
        }
    }
}

// LayerNorm over D=512; y bf16, g/b fp32; writes seq[n][modality][512] bf16.
__global__ __launch_bounds__(256) void ln_kernel(const u16* __restrict__ y,
        const float* __restrict__ g, const float* __restrict__ b,
        u16* __restrict__ seq, int modality) {
    __shared__ float sred[4];
    int n = blockIdx.x, t = threadIdx.x;
    const u16* yr = y + (size_t)n * DD;
    float x0 = bf2f(yr[t]), x1 = bf2f(yr[t + 256]);
    float s = x0 + x1;
    for (int off = 32; off; off >>= 1) s += __shfl_xor(s, off);
    if ((t & 63) == 0) sred[t >> 6] = s;
    __syncthreads();
    float mean = (sred[0] + sred[1] + sred[2] + sred[3]) * (1.0f / DD);
    __syncthreads();
    float d0 = x0 - mean, d1 = x1 - mean;
    float vs = d0 * d0 + d1 * d1;
    for (int off = 32; off; off >>= 1) vs += __shfl_xor(vs, off);
    if ((t & 63) == 0) sred[t >> 6] = vs;
    __syncthreads();
    float var = (sred[0] + sred[1] + sred[2] + sred[3]) * (1.0f / DD);
    float inv = rsqrtf(var + 1e-5f);
    u16* out = seq + (size_t)n * (2 * DD) + modality * DD;
    out[t]       = f2bf(d0 * inv * g[t]       + b[t]);
    out[t + 256] = f2bf(d1 * inv * g[t + 256] + b[t + 256]);
}

// MHA over 2 tokens, 8 heads of 64. One wave per (node, head). ctxm = mean_t(ctx_t).
__global__ __launch_bounds__(256) void attn_kernel(const u16* __restrict__ qkv,
        u16* __restrict__ ctxm) {
    int gid = blockIdx.x * 4 + (threadIdx.x >> 6);
    int lane = threadIdx.x & 63;
    int n = gid >> 3, h = gid & 7;
    const u16* r0 = qkv + (size_t)(n * 2) * 1536;
    const u16* r1 = r0 + 1536;
    float q0 = bf2f(r0[h * 64 + lane]);
    float k0 = bf2f(r0[512 + h * 64 + lane]);
    float v0 = bf2f(r0[1024 + h * 64 + lane]);
    float q1 = bf2f(r1[h * 64 + lane]);
    float k1 = bf2f(r1[512 + h * 64 + lane]);
    float v1 = bf2f(r1[1024 + h * 64 + lane]);
    float p00 = q0 * k0, p01 = q0 * k1, p10 = q1 * k0, p11 = q1 * k1;
    for (int off = 32; off; off >>= 1) {
        p00 += __shfl_xor(p00, off);
        p01 += __shfl_xor(p01, off);
        p10 += __shfl_xor(p10, off);
        p11 += __shfl_xor(p11, off);
    }
    const float sc = 0.125f;  // 1/sqrt(64)
    float s00 = p00 * sc, s01 = p01 * sc, s10 = p10 * sc, s11 = p11 * sc;
    float m0 = fmaxf(s00, s01), e00 = __expf(s00 - m0), e01 = __expf(s01 - m0);
    float a00 = e00 / (e00 + e01), a01 = e01 / (e00 + e01);
    float m1 = fmaxf(s10, s11), e10 = __expf(s10 - m1), e11 = __expf(s11 - m1);
    float a10 = e10 / (e10 + e11), a11 = e11 / (e10 + e11);
    float c0 = a00 * v0 + a01 * v1;
    float c1 = a10 * v0 + a11 * v1;
    ctxm[(size_t)n * 512 + h * 64 + lane] = f2bf(0.5f * (c0 + c1));
}

// Top-16 + softmax stats. Block per row. Register row cache + removal bitmask
// (no LDS row mirror). Per round: wave 0 alone scans the 256 candidates
// (ds_read_b128 + one shfl ladder); owner thread rescans its 32 regs branchless.
__global__ __launch_bounds__(256) void topk_reg(const float* __restrict__ S,
        float* __restrict__ topv, int* __restrict__ topi) {
    __shared__ alignas(16) float curv[256];
    __shared__ alignas(16) int   curi[256];
    __shared__ float sred[8];
    __shared__ int win_i, win_s;
    int row = blockIdx.x, t = threadIdx.x;
    int lane = t & 63, wave = t >> 6;
    const float* Sr = S + (size_t)row * NN;

    // pass 1: load into registers, per-thread max + top-1 (ascending -> earliest tie)
    float4 vals[8];
    float lmax = -3e38f, bestv = -3e38f;
    int besti = 0;
    #pragma unroll
    for (int p = 0; p < 8; ++p) {
        float4 v = *(const float4*)(Sr + p * 1024 + t * 4);
        vals[p] = v;
        #pragma unroll
        for (int u = 0; u < 4; ++u) {
            float x = (&v.x)[u];
            lmax = fmaxf(lmax, x);
            if (x > bestv) { bestv = x; besti = p * 1024 + t * 4 + u; }
        }
    }
    #pragma unroll
    for (int off = 32; off; off >>= 1) lmax = fmaxf(lmax, __shfl_xor(lmax, off));
    if (lane == 0) sred[wave] = lmax;
    __syncthreads();
    float m = fmaxf(fmaxf(sred[0], sred[1]), fmaxf(sred[2], sred[3]));

    // pass 2: branchless sumexp from registers
    float ls = 0.0f;
    #pragma unroll
    for (int p = 0; p < 8; ++p)
        ls += __expf(vals[p].x - m) + __expf(vals[p].y - m)
            + __expf(vals[p].z - m) + __expf(vals[p].w - m);
    #pragma unroll
    for (int off = 32; off; off >>= 1) ls += __shfl_xor(ls, off);
    if (lane == 0) sred[4 + wave] = ls;
    curv[t] = bestv;
    curi[t] = besti;
    __syncthreads();
    float l = sred[4] + sred[5] + sred[6] + sred[7];

    unsigned mask = 0;  // per-thread removed-slot bits (slot = p*4+u)
    for (int r = 0; r < 16; ++r) {
        if (wave == 0) {
            float4 cv = *(const float4*)(curv + lane * 4);
            int4   ci = *(const int4*)(curi + lane * 4);
            float bv = cv.x; int bi = ci.x; int bs = lane * 4;
            if (cv.y > bv || (cv.y == bv && ci.y < bi)) { bv = cv.y; bi = ci.y; bs = lane * 4 + 1; }
            if (cv.z > bv || (cv.z == bv && ci.z < bi)) { bv = cv.z; bi = ci.z; bs = lane * 4 + 2; }
            if (cv.w > bv || (cv.w == bv && ci.w < bi)) { bv = cv.w; bi = ci.w; bs = lane * 4 + 3; }
            #pragma unroll
            for (int off = 32; off; off >>= 1) {
                float ov = __shfl_xor(bv, off);
                int oi = __shfl_xor(bi, off);
                int os = __shfl_xor(bs, off);
                if (ov > bv || (ov == bv && oi < bi)) { bv = ov; bi = oi; bs = os; }
            }
            if (lane == 0) {
                topv[(size_t)row * 16 + r] = __expf(bv - m) / l;
                topi[(size_t)row * 16 + r] = bi;
                win_i = bi;
                win_s = bs;
            }
        }
        __syncthreads();
        if (t == win_s) {
            int wi = win_i;
            mask |= 1u << (((wi >> 10) << 2) | (wi & 3));
            float nb = -3e38f; int ni = 0;
            #pragma unroll
            for (int p = 0; p < 8; ++p) {
                #pragma unroll
                for (int u = 0; u < 4; ++u) {
                    float x = ((mask >> (p * 4 + u)) & 1u) ? -3e38f : (&vals[p].x)[u];
                    if (x > nb) { nb = x; ni = p * 1024 + t * 4 + u; }
                }
            }
            curv[t] = nb;
            curi[t] = ni;
        }
        __syncthreads();
    }
}

// H fp32: zero everything, diag = 1.0f. 8 floats/thread.
__global__ __launch_bounds__(256) void zero_diag_f32(float* __restrict__ H) {
    size_t e = ((size_t)blockIdx.x * 256 + threadIdx.x) * 8;
    int r = (int)(e >> 13);
    int c0 = (int)(e & (NN - 1));
    float4 z0 = make_float4(0.f, 0.f, 0.f, 0.f);
    float4 z1 = z0;
    if (r >= c0 && r < c0 + 8) {
        int o = r - c0;
        float* p = (o < 4) ? ((float*)&z0) + o : ((float*)&z1) + (o - 4);
        *p = 1.0f;
    }
    *(float4*)(H + e) = z0;
    *(float4*)(H + e + 4) = z1;
}

__global__ __launch_bounds__(256) void scatter_kernel(const float* __restrict__ topv,
        const int* __restrict__ topi, float* __restrict__ H) {
    int tk = blockIdx.x * 256 + threadIdx.x;  // 8192*16
    int i = tk >> 4;
    int idx = topi[tk];
    H[(size_t)idx * NN + i] = topv[tk];
}

// ew = max(sigmoid(hidden @ w2 + b2), 1e-8), fp32 out. One wave per node.
__global__ __launch_bounds__(256) void ew_kernel(const u16* __restrict__ hidden,
        const float* __restrict__ w2, const float* __restrict__ b2, float* __restrict__ out) {
    int n = blockIdx.x * 4 + (threadIdx.x >> 6);
    int lane = threadIdx.x & 63;
    const u16* hr = hidden + (size_t)n * 256;
    float s = 0.0f;
    #pragma unroll
    for (int p = 0; p < 4; ++p) s += bf2f(hr[lane + p * 64]) * w2[lane + p * 64];
    for (int off = 32; off; off >>= 1) s += __shfl_xor(s, off);
    if (lane == 0) {
        float z = s + b2[0];
        float sig = 1.0f / (1.0f + __expf(-z));
        out[n] = fmaxf(sig, 1e-8f);
    }
}

extern "C" void kernel_launch(void* const* d_in, const int* in_sizes, int n_in,
                              void* d_out, int out_size, void* d_ws, size_t ws_size,
                              hipStream_t stream) {
    const float* x0    = (const float*)d_in[0];
    const float* x1    = (const float*)d_in[1];
    const float* w_p0  = (const float*)d_in[2];
    const float* b_p0  = (const float*)d_in[3];
    const float* g0    = (const float*)d_in[4];
    const float* beta0 = (const float*)d_in[5];
    const float* w_p1  = (const float*)d_in[6];
    const float* b_p1  = (const float*)d_in[7];
    const float* g1    = (const float*)d_in[8];
    const float* beta1 = (const float*)d_in[9];
    const float* in_w  = (const float*)d_in[10];
    const float* in_b  = (const float*)d_in[11];
    const float* out_w = (const float*)d_in[12];
    const float* out_b = (const float*)d_in[13];
    const float* ew_w1 = (const float*)d_in[14];
    const float* ew_b1 = (const float*)d_in[15];
    const float* ew_w2 = (const float*)d_in[16];
    const float* ew_b2 = (const float*)d_in[17];

    float* Hf = (float*)d_out;                  // [8192][8192] fp32 (256 MB)
    float* ew_out = Hf + (size_t)NN * NN;       // [8192] fp32

    // bf16 staging inside the fp32 H region (dead before S fp32 overwrites all of H).
    u16* Hu = (u16*)d_out;
    u16* x0b    = Hu;                           //   0.. 8 MB
    u16* x1b    = Hu + 4194304;                 //   8..16 MB
    u16* y0     = Hu + 8388608;                 //  16..24 MB
    u16* y1     = Hu + 12582912;                //  24..32 MB
    u16* seq    = Hu + 16777216;                //  32..48 MB   [16384][512]
    u16* qkv    = Hu + 25165824;                //  48..96 MB   [16384][1536]
    u16* ctxm   = Hu + 50331648;                //  96..104 MB
    u16* hidden = Hu + 54525952;                // 104..108 MB  [8192][256]
    u16* wp0b   = Hu + 60817408;                // 116 MB.. weights (3.25 MB)
    u16* wp1b   = wp0b + 262144;
    u16* inwb   = wp1b + 262144;                // [1536][512]
    u16* outwb  = inwb + 786432;
    u16* eww1b  = outwb + 262144;               // [256][512]
    // ws: survives the S GEMM (9 MB)
    char* ws = (char*)d_ws;
    u16* fusedB = (u16*)ws;                     // [8192][512] bf16, 8 MB
    float* topv = (float*)(ws + (8u << 20));    // [8192][16]
    int*   topi = (int*)(ws + (8u << 20) + 524288);

    dim3 blk(256);
    // 0: fp32 -> bf16 for all MFMA operands
    cvt_kernel<<<dim3(2048), blk, 0, stream>>>(x0, x0b, 4194304);
    cvt_kernel<<<dim3(2048), blk, 0, stream>>>(x1, x1b, 4194304);
    cvt_kernel<<<dim3(128),  blk, 0, stream>>>(w_p0, wp0b, 262144);
    cvt_kernel<<<dim3(128),  blk, 0, stream>>>(w_p1, wp1b, 262144);
    cvt_kernel<<<dim3(384),  blk, 0, stream>>>(in_w, inwb, 786432);
    cvt_kernel<<<dim3(128),  blk, 0, stream>>>(out_w, outwb, 262144);
    cvt_kernel<<<dim3(64),   blk, 0, stream>>>(ew_w1, eww1b, 131072);
    // 1-2: modality projections (relu fused)
    gemm_bt<true, true, false><<<dim3(4, 64), blk, 0, stream>>>(x0b, wp0b, b_p0, y0, NN, DD, DD);
    gemm_bt<true, true, false><<<dim3(4, 64), blk, 0, stream>>>(x1b, wp1b, b_p1, y1, NN, DD, DD);
    // 3-4: LayerNorm -> seq
    ln_kernel<<<dim3(NN), blk, 0, stream>>>(y0, g0, beta0, seq, 0);
    ln_kernel<<<dim3(NN), blk, 0, stream>>>(y1, g1, beta1, seq, 1);
    // 5: qkv = seq @ in_w^T + in_b  (M=16384, N=1536)
    gemm_bt<false, true, false><<<dim3(12, 128), blk, 0, stream>>>(seq, inwb, in_b, qkv, 2 * NN, 1536, DD);
    // 6: attention -> ctxm = mean_t ctx
    attn_kernel<<<dim3(NN * 8 / 4), blk, 0, stream>>>(qkv, ctxm);
    // 7: fused = ctxm @ out_w^T + out_b (out-proj commutes with token mean)
    gemm_bt<false, true, false><<<dim3(4, 64), blk, 0, stream>>>(ctxm, outwb, out_b, fusedB, NN, DD, DD);
    // 8: hidden = relu(fused @ ew_w1^T + ew_b1)
    gemm_bt<true, true, false><<<dim3(2, 64), blk, 0, stream>>>(fusedB, eww1b, ew_b1, hidden, NN, 256, DD);
    // 9: ew -> fp32 tail of d_out
    ew_kernel<<<dim3(NN / 4), blk, 0, stream>>>(hidden, ew_w2, ew_b2, ew_out);
    // 10: S = fused @ fused^T, fp32, into the FULL H region (staging all dead)
    gemm_bt<false, false, true><<<dim3(64, 64), blk, 0, stream>>>(fusedB, fusedB, nullptr, Hf, NN, NN, DD);
    // 11: per-row softmax stats + top-16 (register cache + bitmask, wave-0 argmax)
    topk_reg<<<dim3(NN), blk, 0, stream>>>(Hf, topv, topi);
    // 12: H := 0 (fp32), diag := 1.0f
    zero_diag_f32<<<dim3(NN * NN / 8 / 256), blk, 0, stream>>>(Hf);
    // 13: H[idx[i,j], i] = vals[i,j]
    scatter_kernel<<<dim3(NN * 16 / 256), blk, 0, stream>>>(topv, topi, Hf);
}